// Round 4
// baseline (163.035 us; speedup 1.0000x reference)
//
#include <hip/hip_runtime.h>

#define NSEG 128
#define SSTEPS 32
#define TDIM 32
#define NGC 4              // LDS accumulator copies (group g uses copy g&3)
#define DROWS 39           // stored rows = logical s in [-2,36]; s>=32 junk
#define SPB 16             // splits per segment
#define CSTR (DROWS * TDIM)   // 1248 floats per copy
#define UNR 2              // software-pipeline batch width (nodes per thread)

// ---------------- Kernel: per-(segment,split) tiles, fused epilogue ---------
// Difference-domain accumulation: per (node,t), d/ds of the sigmoid step
// profile has exactly 3 nonzero entries at consecutive rows summing to 1.
// R4 fix vs R3's 103us kernel:
//   * R3's atomicAdd(__shared__ float*) went through a GENERIC pointer ->
//     hipcc emitted a flat-atomic CAS retry loop (~2000cyc serial/node,
//     VALUBusy 5%, bank-conflicts 0: pure flat/lgkm stall). Replaced with
//     inline-asm ds_add_f32 (fire-and-forget, untracked, no rtn): the low
//     32 bits of a generic LDS pointer ARE the LDS byte offset on gfx9+.
//   * Copies 2 -> 4 (halve cross-group same-address collisions). LDS =
//     4*1248*4 + 8 = 19976 B -> 20480 granule -> exactly 8 blocks/CU.
//   * Explicit s_waitcnt lgkmcnt(0) before the fold barrier (inline-asm DS
//     ops are invisible to the compiler's waitcnt insertion).
__global__ __launch_bounds__(256, 8) void ect_kernel(
    const float* __restrict__ x,       // [N,3]
    const int*   __restrict__ idx,     // [N] int32 or int64 (N even; detected)
    const float* __restrict__ v,       // [3,32]
    const float* __restrict__ lin,     // [32]
    const int*   __restrict__ scale_p, // [1]
    float*       __restrict__ out,     // [NSEG,32,32], pre-zeroed
    int N)
{
    __shared__ float d[NGC][DROWS][TDIM];   // 19.5 KB
    __shared__ int s_bounds[2];

    const int tid = threadIdx.x;
    const unsigned bx = blockIdx.x;
    const int b = bx >> 4;            // segment
    const int j = bx & (SPB - 1);     // split

    // ---- wave-parallel segment-boundary search (wave 0) ----
    // halves: lanes 0-31 -> target b, lanes 32-63 -> target b+1
    if (tid < 64) {
        const int L = tid & 31;
        const int h = tid >> 5;
        const int target = b + h;
        const int g0 = (int)(((long long)target * N) >> 7);  // *N/128 guess

        const int hi_last = idx[N - 1];          // ==0 iff int64 (N even)
        int p1 = g0 - 1024 + 64 * L;
        int pc1 = min(max(p1, 0), N - 1);
        int val32 = idx[pc1];
        const bool is64 = (hi_last == 0);
        int val = is64 ? idx[2 * pc1] : val32;

        bool pred1 = (p1 < 0) ? true : ((p1 >= N) ? false : (val < target));
        unsigned long long m1 = __ballot(pred1);
        unsigned hm1 = (unsigned)(m1 >> (h * 32));

        if (hm1 == 0u || hm1 == 0xFFFFFFFFu) {
            if (L == 0) {                       // rare fallback: serial search
                int lo = 0, hi = N;
                while (lo < hi) {
                    int mid = (lo + hi) >> 1;
                    int vv = is64 ? idx[2 * mid] : idx[mid];
                    if (vv < target) lo = mid + 1; else hi = mid;
                }
                s_bounds[h] = lo;
            }
        } else {
            const int A = g0 - 1024 + 64 * (31 - __builtin_clz(hm1));
            int p2 = A + 1 + 2 * L;
            int pc2 = min(max(p2, 0), N - 1);
            int v2 = is64 ? idx[2 * pc2] : idx[pc2];
            bool pred2 = (p2 < 0) ? true : ((p2 >= N) ? false : (v2 < target));
            unsigned long long m2 = __ballot(pred2);
            unsigned hm2 = (unsigned)(m2 >> (h * 32));
            const int B = hm2 ? (A + 1 + 2 * (31 - __builtin_clz(hm2))) : A;
            int p3 = B + 1;
            int pc3 = min(p3, N - 1);
            int v3 = is64 ? idx[2 * pc3] : idx[pc3];
            bool pred3 = (p3 >= N) ? false : (v3 < target);
            if (L == 0) s_bounds[h] = pred3 ? (B + 2) : (B + 1);
        }
    }
    // zero-init accumulators (float4): NGC*CSTR/4 = 1248 quads
    {
        float4* dz = (float4*)d;
        for (int i = tid; i < NGC * CSTR / 4; i += 256)
            dz[i] = make_float4(0.f, 0.f, 0.f, 0.f);
    }

    const float lin0 = lin[0];
    const float step = lin[1] - lin0;
    const float inv_step = 1.0f / step;
    const float negl0 = -lin0 * inv_step;
    const float scale = (float)scale_p[0];
    const float zstep = scale * step;          // ~35.48
    const float C = __expf(zstep);             // e^{zstep}, finite

    const int t = tid & 31;
    const int g = tid >> 5;                    // 32-thread group id, 0..7
    const float v0 = v[t], v1 = v[TDIM + t], v2 = v[2 * TDIM + t];
    // LDS byte offset of this thread's column in its copy: on gfx9-lineage
    // the low 32 bits of a generic pointer to LDS are the LDS byte offset.
    const unsigned dg_off =
        (unsigned)(unsigned long long)(const void*)&d[g & (NGC - 1)][0][t];

    __syncthreads();

    const int start = s_bounds[0], end = s_bounds[1];
    const int cnt = end - start;
    const int chunk = (cnt + SPB - 1) / SPB;
    const int k0 = start + j * chunk;
    const int k1 = min(k0 + chunk, end);
    const int NGRP = 8;                        // groups per block

    // one node: weights + 3 fire-and-forget ds_add_f32
    auto process = [&](float x0, float x1, float x2) {
        const float nh = fmaf(x0, v0, fmaf(x1, v1, x2 * v2));

        float u = fmaf(nh, inv_step, negl0);
        u = fminf(fmaxf(u, -2.0f), 34.0f);
        const float sf = floorf(u);
        const int base = (int)sf + 2;                 // 0..36 (guard rows 0,1)

        // single exp serves both bracketing sigmoids; fast v_rcp_f32
        const float E = __expf((sf - u) * zstep);     // e^{z0} in (0,1]
        const float rc = __builtin_amdgcn_rcpf(1.0f + E);
        const float sig0  = E * rc;
        const float sig1c = __builtin_amdgcn_rcpf(fmaf(E, C, 1.0f));

        const float w0 = sig0;
        const float w1 = 1.0f - sig0 - sig1c;
        const float w2 = sig1c;                       // sums to 1

        const unsigned a = dg_off + (unsigned)(base * (TDIM * 4));
        asm volatile("ds_add_f32 %0, %1"             :: "v"(a), "v"(w0));
        asm volatile("ds_add_f32 %0, %1 offset:128"  :: "v"(a), "v"(w1));
        asm volatile("ds_add_f32 %0, %1 offset:256"  :: "v"(a), "v"(w2));
    };

    // ---- batched software pipeline over this thread's nodes ----
    {
        int k = k0 + g;
        const int nit = (k < k1) ? ((k1 - k) + NGRP - 1) / NGRP : 0;
        const int nb = nit / UNR;                 // full batches

        float cx[UNR][3];
        if (nb > 0) {
            #pragma unroll
            for (int i = 0; i < UNR; ++i) {
                const int kk = k + i * NGRP;
                cx[i][0] = x[kk * 3 + 0];
                cx[i][1] = x[kk * 3 + 1];
                cx[i][2] = x[kk * 3 + 2];
            }
        }
        for (int bi = 0; bi < nb; ++bi) {
            const int knext = k + UNR * NGRP;
            const bool more = (bi + 1 < nb);
            float nx[UNR][3];
            #pragma unroll
            for (int i = 0; i < UNR; ++i) {
                const int kk = more ? (knext + i * NGRP) : k;
                nx[i][0] = x[kk * 3 + 0];
                nx[i][1] = x[kk * 3 + 1];
                nx[i][2] = x[kk * 3 + 2];
            }
            #pragma unroll
            for (int i = 0; i < UNR; ++i)
                process(cx[i][0], cx[i][1], cx[i][2]);
            #pragma unroll
            for (int i = 0; i < UNR; ++i) {
                cx[i][0] = nx[i][0]; cx[i][1] = nx[i][1]; cx[i][2] = nx[i][2];
            }
            k = knext;
        }
        for (k = k0 + g + nb * UNR * NGRP; k < k1; k += NGRP)
            process(x[k * 3 + 0], x[k * 3 + 1], x[k * 3 + 2]);
    }
    // drain untracked inline-asm DS ops, then barrier
    asm volatile("s_waitcnt lgkmcnt(0)" ::: "memory");
    __syncthreads();

    // fold copies 1..3 into copy 0 (float4): CSTR/4 = 312 quads
    {
        float4* c0 = (float4*)d;
        for (int i = tid; i < CSTR / 4; i += 256) {
            float4 a = c0[i];
            #pragma unroll
            for (int gg = 1; gg < NGC; ++gg) {
                const float4 bq = ((const float4*)((const float*)d + gg * CSTR))[i];
                a.x += bq.x; a.y += bq.y; a.z += bq.z; a.w += bq.w;
            }
            c0[i] = a;
        }
    }
    __syncthreads();

    // prefix-sum diffs over stored rows per t (32 threads), in place.
    // seed with guard rows 0,1 (logical s<0 -> fold into s=0).
    if (tid < TDIM) {
        float* df = (float*)d;
        float run = df[tid] + df[32 + tid];
        #pragma unroll
        for (int s = 0; s < SSTEPS; ++s) {
            run += df[(s + 2) * 32 + tid];
            df[(s + 2) * 32 + tid] = run;
        }
    }
    __syncthreads();

    // fused reduction: atomicAdd tile into out (coalesced, 4 cells/thread);
    // stored rows 2..33 hold cumulative for s=0..31 -> offset +64 floats.
    {
        const float* df = (const float*)d;
        float* ob = out + (size_t)b * (SSTEPS * TDIM);
        #pragma unroll
        for (int q = 0; q < 4; ++q)
            atomicAdd(&ob[q * 256 + tid], df[64 + q * 256 + tid]);
    }
}

extern "C" void kernel_launch(void* const* d_in, const int* in_sizes, int n_in,
                              void* d_out, int out_size, void* d_ws, size_t ws_size,
                              hipStream_t stream) {
    const float* x     = (const float*)d_in[0];
    const int*   index = (const int*)d_in[1];
    const float* v     = (const float*)d_in[2];
    const float* lin   = (const float*)d_in[3];
    const int*   scale = (const int*)d_in[4];
    float* out = (float*)d_out;
    const int N = in_sizes[0] / 3;   // x is [N,3]

    hipMemsetAsync(d_out, 0, (size_t)out_size * sizeof(float), stream);
    ect_kernel<<<NSEG * SPB, 256, 0, stream>>>(x, index, v, lin, scale, out, N);
}

// Round 5
// 72.972 us; speedup vs baseline: 2.2342x; 2.2342x over previous
//
#include <hip/hip_runtime.h>

#define NSEG 128
#define SSTEPS 32
#define TDIM 32
#define NG 8               // exclusive banked accumulator copies = groups/block
#define DROWS 35           // rows 0..34: 0..1 guard (s<0), 2..33 = s 0..31, 34 junk
#define SPB 8              // splits per segment
#define CSTR (DROWS * TDIM)   // 1120 floats per copy
#define UNR 4              // software-pipeline batch width (nodes per thread)

// ---------------- Kernel: per-(segment,split) tiles, fused epilogue ---------
// R5: DS-pipe minimization. R3/R4 proved LDS atomics run ~0.73 lane-ops/cyc/CU
// (19.2M ds_add lane-ops = 103us); R2's exclusive RMW (4 DS instr / 2 nodes)
// was also DS-bound at ~14us. This version cuts DS work ~4x:
//   * 2-tap exact decomposition: zstep=scale*step~35.5 so the sigmoid
//     transition spans 0.12 steps -> per (node,t) the d/ds profile is
//     EXACTLY {a at row r, 1-a at row r+1}, r=rint(u), a=E/(1+E),
//     E=e^{(r-u)*zstep} (|arg|<=17.7, finite). Dropped taps are <2e-8.
//     DS per node: ds_read2_b32 + ds_write2_b32 (2 instr vs 4).
//   * Saturation skips (exact): r>=32 -> taps in s>=32 junk, skip all
//     (no exp, no DS, ~24% of pairs). r==-2 -> taps are guard mass
//     summing to 1.0 -> register cnt, one ds_write per lane at the end
//     into row 0 (exclusively the counter row). Mid path ~52% of lanes.
//   * Exclusive per-group copies (NO LDS atomics), SPB=8, UNR=4 (R2 frame).
__global__ __launch_bounds__(256) void ect_kernel(
    const float* __restrict__ x,       // [N,3]
    const int*   __restrict__ idx,     // [N] int32 or int64 (N even; detected)
    const float* __restrict__ v,       // [3,32]
    const float* __restrict__ lin,     // [32]
    const int*   __restrict__ scale_p, // [1]
    float*       __restrict__ out,     // [NSEG,32,32], pre-zeroed
    int N)
{
    __shared__ float d[NG][DROWS][TDIM];   // 35 KB
    __shared__ int s_bounds[2];

    const int tid = threadIdx.x;
    const unsigned bx = blockIdx.x;
    const int b = bx >> 3;            // segment
    const int j = bx & (SPB - 1);     // split

    // ---- wave-parallel segment-boundary search (wave 0) ----
    // halves: lanes 0-31 -> target b, lanes 32-63 -> target b+1
    if (tid < 64) {
        const int L = tid & 31;
        const int h = tid >> 5;
        const int target = b + h;
        const int g0 = (int)(((long long)target * N) >> 7);  // *N/128 guess

        const int hi_last = idx[N - 1];          // ==0 iff int64 (N even)
        int p1 = g0 - 1024 + 64 * L;
        int pc1 = min(max(p1, 0), N - 1);
        int val32 = idx[pc1];
        const bool is64 = (hi_last == 0);
        int val = is64 ? idx[2 * pc1] : val32;

        bool pred1 = (p1 < 0) ? true : ((p1 >= N) ? false : (val < target));
        unsigned long long m1 = __ballot(pred1);
        unsigned hm1 = (unsigned)(m1 >> (h * 32));

        if (hm1 == 0u || hm1 == 0xFFFFFFFFu) {
            if (L == 0) {                       // rare fallback: serial search
                int lo = 0, hi = N;
                while (lo < hi) {
                    int mid = (lo + hi) >> 1;
                    int vv = is64 ? idx[2 * mid] : idx[mid];
                    if (vv < target) lo = mid + 1; else hi = mid;
                }
                s_bounds[h] = lo;
            }
        } else {
            const int A = g0 - 1024 + 64 * (31 - __builtin_clz(hm1));
            int p2 = A + 1 + 2 * L;
            int pc2 = min(max(p2, 0), N - 1);
            int v2 = is64 ? idx[2 * pc2] : idx[pc2];
            bool pred2 = (p2 < 0) ? true : ((p2 >= N) ? false : (v2 < target));
            unsigned long long m2 = __ballot(pred2);
            unsigned hm2 = (unsigned)(m2 >> (h * 32));
            const int B = hm2 ? (A + 1 + 2 * (31 - __builtin_clz(hm2))) : A;
            int p3 = B + 1;
            int pc3 = min(p3, N - 1);
            int v3 = is64 ? idx[2 * pc3] : idx[pc3];
            bool pred3 = (p3 >= N) ? false : (v3 < target);
            if (L == 0) s_bounds[h] = pred3 ? (B + 2) : (B + 1);
        }
    }
    // zero-init accumulators (float4): NG*CSTR/4 = 2240 quads
    {
        float4* dz = (float4*)d;
        for (int i = tid; i < NG * CSTR / 4; i += 256)
            dz[i] = make_float4(0.f, 0.f, 0.f, 0.f);
    }

    const float lin0 = lin[0];
    const float step = lin[1] - lin0;
    const float inv_step = 1.0f / step;
    const float negl0 = -lin0 * inv_step;
    const float scale = (float)scale_p[0];
    const float zstep = scale * step;          // ~35.48

    const int t = tid & 31;
    const int g = tid >> 5;                    // group 0..7, exclusive copy g
    const float v0 = v[t], v1 = v[TDIM + t], v2 = v[2 * TDIM + t];
    float* dg = &d[g][0][t];                   // row stride = 32 floats

    __syncthreads();

    const int start = s_bounds[0], end = s_bounds[1];
    const int cnt_n = end - start;
    const int chunk = (cnt_n + SPB - 1) / SPB;
    const int k0 = start + j * chunk;
    const int k1 = min(k0 + chunk, end);

    float cnt = 0.f;                           // mass fully below s=0

    // one node: 2-tap exact decomposition, exclusive LDS RMW (2 DS instr)
    auto process = [&](float x0, float x1, float x2) {
        const float nh = fmaf(x0, v0, fmaf(x1, v1, x2 * v2));

        float u = fmaf(nh, inv_step, negl0);
        u = fminf(fmaxf(u, -2.0f), 34.0f);     // v_med3
        const float rf = rintf(u);             // v_rndne; r in [-2,34]

        if (rf >= 32.0f) return;               // taps land at s>=32: discard
        if (rf <= -2.0f) { cnt += 1.0f; return; }  // taps sum to 1 below s=0

        // a = sigmoid at the single non-saturated knot r
        const float E = __expf((rf - u) * zstep);     // arg in [-17.75,17.75]
        const float a = E * __builtin_amdgcn_rcpf(1.0f + E);

        const int row = (int)rf + 2;           // 1..33
        float* p = dg + row * 32;
        const float a0 = p[0];                 // ds_read2_b32 (offset0 0, offset1 32)
        const float a1 = p[32];
        p[0]  = a0 + a;                        // ds_write2_b32
        p[32] = a1 + (1.0f - a);
    };

    // ---- 4-wide batched software pipeline over this thread's nodes ----
    {
        int k = k0 + g;
        const int nit = (k < k1) ? ((k1 - k) + NG - 1) / NG : 0;
        const int nb = nit / UNR;                 // full batches

        float cx[UNR][3];
        if (nb > 0) {
            #pragma unroll
            for (int i = 0; i < UNR; ++i) {
                const int kk = k + i * NG;
                cx[i][0] = x[kk * 3 + 0];
                cx[i][1] = x[kk * 3 + 1];
                cx[i][2] = x[kk * 3 + 2];
            }
        }
        for (int bi = 0; bi < nb; ++bi) {
            const int knext = k + UNR * NG;
            const bool more = (bi + 1 < nb);
            float nx[UNR][3];
            #pragma unroll
            for (int i = 0; i < UNR; ++i) {
                const int kk = more ? (knext + i * NG) : k;
                nx[i][0] = x[kk * 3 + 0];
                nx[i][1] = x[kk * 3 + 1];
                nx[i][2] = x[kk * 3 + 2];
            }
            #pragma unroll
            for (int i = 0; i < UNR; ++i)
                process(cx[i][0], cx[i][1], cx[i][2]);
            #pragma unroll
            for (int i = 0; i < UNR; ++i) {
                cx[i][0] = nx[i][0]; cx[i][1] = nx[i][1]; cx[i][2] = nx[i][2];
            }
            k = knext;
        }
        for (k = k0 + g + nb * UNR * NG; k < k1; k += NG)
            process(x[k * 3 + 0], x[k * 3 + 1], x[k * 3 + 2]);
    }
    // flush the below-range counter: row 0 is exclusively the counter row
    dg[0] = cnt;
    __syncthreads();

    // fold copies 1..7 into copy 0 (float4): CSTR/4 = 280 quads
    {
        float4* c0 = (float4*)d;
        for (int i = tid; i < CSTR / 4; i += 256) {
            float4 a = c0[i];
            #pragma unroll
            for (int gg = 1; gg < NG; ++gg) {
                const float4 bq = ((const float4*)((const float*)d + gg * CSTR))[i];
                a.x += bq.x; a.y += bq.y; a.z += bq.z; a.w += bq.w;
            }
            c0[i] = a;
        }
    }
    __syncthreads();

    // prefix-sum diffs over stored rows per t (32 threads), in place.
    // seed with guard rows 0,1 (mass below s=0 folds into s=0).
    if (tid < TDIM) {
        float* df = (float*)d;
        float run = df[tid] + df[32 + tid];
        #pragma unroll
        for (int s = 0; s < SSTEPS; ++s) {
            run += df[(s + 2) * 32 + tid];
            df[(s + 2) * 32 + tid] = run;
        }
    }
    __syncthreads();

    // fused reduction: atomicAdd tile into out (coalesced, 4 cells/thread);
    // stored rows 2..33 hold cumulative for s=0..31 -> offset +64 floats.
    {
        const float* df = (const float*)d;
        float* ob = out + (size_t)b * (SSTEPS * TDIM);
        #pragma unroll
        for (int q = 0; q < 4; ++q)
            atomicAdd(&ob[q * 256 + tid], df[64 + q * 256 + tid]);
    }
}

extern "C" void kernel_launch(void* const* d_in, const int* in_sizes, int n_in,
                              void* d_out, int out_size, void* d_ws, size_t ws_size,
                              hipStream_t stream) {
    const float* x     = (const float*)d_in[0];
    const int*   index = (const int*)d_in[1];
    const float* v     = (const float*)d_in[2];
    const float* lin   = (const float*)d_in[3];
    const int*   scale = (const int*)d_in[4];
    float* out = (float*)d_out;
    const int N = in_sizes[0] / 3;   // x is [N,3]

    hipMemsetAsync(d_out, 0, (size_t)out_size * sizeof(float), stream);
    ect_kernel<<<NSEG * SPB, 256, 0, stream>>>(x, index, v, lin, scale, out, N);
}